// Round 1
// baseline (3364.326 us; speedup 1.0000x reference)
//
#include <hip/hip_runtime.h>
#include <math.h>

// Problem constants (Posit_Drmm_Modeler)
#define VB  64      // batch
#define NSS 50      // sentences per doc
#define LSS 60      // sentence length
#define LQQ 32      // question length
#define DD  300     // embedding dim
#define FF  256     // filters
// LDS strides
#define SEST 308    // se row stride (floats): 308%32=20 -> 8 rows apart share banks (8-way worst)
#define SCST 264    // sc row stride (bf16 elems): 8B-aligned rows for uint2 reads

__device__ __forceinline__ unsigned short f2bf(float v) {
    unsigned int x = __float_as_uint(v);
    x += 0x7fffu + ((x >> 16) & 1u);          // RNE
    return (unsigned short)(x >> 16);
}
__device__ __forceinline__ float bflo(unsigned int u) { return __uint_as_float(u << 16); }
__device__ __forceinline__ float bfhi(unsigned int u) { return __uint_as_float(u & 0xffff0000u); }

// ---------------- k_qprep: gather question embeddings (fp32, rows 32..33 zero-padded) + row inv-norms
__global__ __launch_bounds__(256) void k_qprep(const int* __restrict__ question,
                                               const float* __restrict__ embeds,
                                               float* __restrict__ qe,
                                               float* __restrict__ q_inv) {
    const int b = blockIdx.x, tid = threadIdx.x, lane = tid & 63, wv = tid >> 6;
    float* qeb = qe + (size_t)b * 34 * DD;
    for (int idx = tid; idx < 34 * DD; idx += 256) {
        int r = idx / DD, d = idx - r * DD;
        float v = 0.f;
        if (r < LQQ) v = embeds[(size_t)question[b * LQQ + r] * DD + d];
        qeb[idx] = v;
    }
    __syncthreads();
    for (int row = wv; row < LQQ; row += 4) {
        float s = 0.f;
        for (int d = lane; d < DD; d += 64) { float v = qeb[row * DD + d]; s += v * v; }
        #pragma unroll
        for (int off = 32; off > 0; off >>= 1) s += __shfl_down(s, off, 64);
        if (lane == 0) q_inv[b * LQQ + row] = 1.f / sqrtf(s);
    }
}

// ---------------- k_qconv: question conv (forward window, zero pad at end) + inv-norm over F
// grid: VB*8, each WG does 4 l-positions x 256 filters. thread = filter.
__global__ __launch_bounds__(256) void k_qconv(const float* __restrict__ qe,
                                               const float* __restrict__ filters,
                                               float* __restrict__ qc,
                                               float* __restrict__ qc_inv) {
    const int blk = blockIdx.x, b = blk >> 3, l0 = (blk & 7) * 4;
    const int tid = threadIdx.x;
    __shared__ __align__(16) float sq[6 * DD];   // rows l0..l0+5 (<=33, padded rows are zero)
    __shared__ float red[256];
    const float* qeb = qe + (size_t)b * 34 * DD + (size_t)l0 * DD;
    for (int idx = tid; idx < 6 * DD; idx += 256) sq[idx] = qeb[idx];
    __syncthreads();
    const float* frow = filters + (size_t)tid * 900;
    float acc[4] = {0.f, 0.f, 0.f, 0.f};
    for (int t = 0; t < 3; ++t) {
        const float* ft = frow + t * DD;
        const float* st = sq + t * DD;
        for (int d4 = 0; d4 < 75; ++d4) {
            float4 w = *(const float4*)(ft + d4 * 4);
            #pragma unroll
            for (int i = 0; i < 4; ++i) {
                float4 x = *(const float4*)(st + i * DD + d4 * 4);
                acc[i] += w.x * x.x + w.y * x.y + w.z * x.z + w.w * x.w;
            }
        }
    }
    #pragma unroll
    for (int i = 0; i < 4; ++i)
        qc[((size_t)b * LQQ + l0 + i) * FF + tid] = acc[i];
    for (int i = 0; i < 4; ++i) {
        red[tid] = acc[i] * acc[i];
        __syncthreads();
        for (int s = 128; s > 0; s >>= 1) {
            if (tid < s) red[tid] += red[tid + s];
            __syncthreads();
        }
        if (tid == 0) qc_inv[(size_t)b * LQQ + l0 + i] = 1.f / sqrtf(red[0]);
        __syncthreads();
    }
}

// ---------------- k_sent: fully fused per-(b,n): gather + sim_ins + conv + sim_sen + pool + sigmoid-mean
__global__ __launch_bounds__(256) void k_sent(
    const int* __restrict__ sentences, const int* __restrict__ question,
    const float* __restrict__ embeds, const float* __restrict__ filters,
    const float* __restrict__ qe, const float* __restrict__ q_inv,
    const float* __restrict__ qc, const float* __restrict__ qc_inv,
    const float* __restrict__ W6, const float* __restrict__ b1,
    float* __restrict__ d_out) {
    const int blk = blockIdx.x;
    const int b = blk / NSS, n = blk - b * NSS;
    const int tid = threadIdx.x, lane = tid & 63, wv = tid >> 6;

    __shared__ __align__(16) float sef[34 * SEST];   // 41,888 B; later reused as bf16 sc (60*264*2=31,680 B)
    __shared__ float sim[LQQ * 65];                  // 8,320 B; reused ins -> sen
    __shared__ float sinv[LSS];
    __shared__ float scn[LSS];
    __shared__ int   sid[LSS];
    __shared__ int   qid[LQQ];
    __shared__ float qm[LQQ];
    __shared__ float qiv[LQQ];
    __shared__ float qciv[LQQ];
    __shared__ float featq[LQQ][6];
    __shared__ float pr[LQQ];
    unsigned short* scb = (unsigned short*)sef;

    if (tid < LSS) { sid[tid] = sentences[((size_t)b * NSS + n) * LSS + tid]; scn[tid] = 0.f; }
    if (tid < LQQ) {
        int qi = question[b * LQQ + tid];
        qid[tid] = qi; qm[tid] = qi > 0 ? 1.f : 0.f;
        qiv[tid]  = q_inv[b * LQQ + tid];
        qciv[tid] = qc_inv[b * LQQ + tid];
    }
    __syncthreads();

    float accA[32], accB[28];
    #pragma unroll
    for (int i = 0; i < 32; ++i) accA[i] = 0.f;
    #pragma unroll
    for (int i = 0; i < 28; ++i) accB[i] = 0.f;

    const float* frow = filters + (size_t)tid * 900;
    const float* qeb  = qe + (size_t)b * 34 * DD;

    // ======== PASS 0: stage sentence rows 0..33 (all real) ========
    for (int idx = tid; idx < 34 * DD; idx += 256) {
        int r = idx / DD, d = idx - r * DD;
        sef[r * SEST + d] = embeds[(size_t)sid[r] * DD + d];
    }
    __syncthreads();
    for (int row = wv; row < 34; row += 4) {          // inv-norms rows 0..33
        float s = 0.f;
        for (int d = lane; d < DD; d += 64) { float v = sef[row * SEST + d]; s += v * v; }
        #pragma unroll
        for (int off = 32; off > 0; off >>= 1) s += __shfl_down(s, off, 64);
        if (lane == 0) sinv[row] = 1.f / sqrtf(s);
    }
    __syncthreads();
    // sim_ins for l = 0..33 (32 lanes share a row -> broadcast LDS reads)
    for (int p = tid; p < LQQ * 34; p += 256) {
        int l = p >> 5, q = p & 31;
        const float* srow = &sef[l * SEST];
        const float* qrow = qeb + q * DD;
        float s = 0.f;
        for (int k = 0; k < DD; k += 4) {
            float4 x = *(const float4*)(srow + k);
            float4 y = *(const float4*)(qrow + k);
            s += x.x * y.x + x.y * y.y + x.z * y.z + x.w * y.w;
        }
        sim[q * 65 + l] = s * qiv[q] * sinv[l] * qm[q] * (sid[l] > 0 ? 1.f : 0.f);
    }
    // conv accumulate l = 0..31 (windows within rows 0..33)
    for (int t = 0; t < 3; ++t) {
        const float* ft = frow + t * DD;
        for (int d4 = 0; d4 < 75; ++d4) {
            float4 w = *(const float4*)(ft + d4 * 4);
            const float* base = &sef[t * SEST + d4 * 4];
            #pragma unroll
            for (int i = 0; i < 32; ++i) {
                float4 x = *(const float4*)(base + i * SEST);
                accA[i] += w.x * x.x + w.y * x.y + w.z * x.z + w.w * x.w;
            }
        }
    }
    __syncthreads();

    // ======== PASS 1: stage rows 32..63 into slots r=row-32 (rows >=60 are zero) ========
    for (int idx = tid; idx < 32 * DD; idx += 256) {
        int r = idx / DD, d = idx - r * DD;
        int row = 32 + r;
        float v = 0.f;
        if (row < LSS) v = embeds[(size_t)sid[row] * DD + d];
        sef[r * SEST + d] = v;
    }
    __syncthreads();
    for (int row = 34 + wv; row < LSS; row += 4) {    // inv-norms rows 34..59
        float s = 0.f; int r = row - 32;
        for (int d = lane; d < DD; d += 64) { float v = sef[r * SEST + d]; s += v * v; }
        #pragma unroll
        for (int off = 32; off > 0; off >>= 1) s += __shfl_down(s, off, 64);
        if (lane == 0) sinv[row] = 1.f / sqrtf(s);
    }
    __syncthreads();
    // sim_ins for l = 34..59
    for (int p = tid; p < LQQ * 26; p += 256) {
        int l = 34 + (p >> 5), q = p & 31;
        const float* srow = &sef[(l - 32) * SEST];
        const float* qrow = qeb + q * DD;
        float s = 0.f;
        for (int k = 0; k < DD; k += 4) {
            float4 x = *(const float4*)(srow + k);
            float4 y = *(const float4*)(qrow + k);
            s += x.x * y.x + x.y * y.y + x.z * y.z + x.w * y.w;
        }
        sim[q * 65 + l] = s * qiv[q] * sinv[l] * qm[q] * (sid[l] > 0 ? 1.f : 0.f);
    }
    // conv accumulate l = 32..59 (l=32+i, window slot = i+t)
    for (int t = 0; t < 3; ++t) {
        const float* ft = frow + t * DD;
        for (int d4 = 0; d4 < 75; ++d4) {
            float4 w = *(const float4*)(ft + d4 * 4);
            const float* base = &sef[t * SEST + d4 * 4];
            #pragma unroll
            for (int i = 0; i < 28; ++i) {
                float4 x = *(const float4*)(base + i * SEST);
                accB[i] += w.x * x.x + w.y * x.y + w.z * x.z + w.w * x.w;
            }
        }
    }
    __syncthreads();   // sef reads done; sim_ins complete

    // -------- pool ins + exact-match (oh) channel --------
    if (tid < LQQ) {
        int q = tid;
        float t0 = -1e30f, t1 = -1e30f, t2 = -1e30f, t3 = -1e30f, t4 = -1e30f;
        for (int l = 0; l < LSS; ++l) {
            float v = sim[q * 65 + l];
            if (v > t4) {
                if (v > t0)      { t4 = t3; t3 = t2; t2 = t1; t1 = t0; t0 = v; }
                else if (v > t1) { t4 = t3; t3 = t2; t2 = t1; t1 = v; }
                else if (v > t2) { t4 = t3; t3 = t2; t2 = v; }
                else if (v > t3) { t4 = t3; t3 = v; }
                else               t4 = v;
            }
        }
        featq[q][0] = t0;
        featq[q][1] = (t0 + t1 + t2 + t3 + t4) * 0.2f;
        // oh channel: cos>=1-1e-5  <=>  identical token id (incl. pad==pad), UNMASKED as in ref
        int qi = qid[q], c = 0;
        for (int l = 0; l < LSS; ++l) c += (sid[l] == qi) ? 1 : 0;
        featq[q][4] = c > 0 ? 1.f : 0.f;
        featq[q][5] = (float)(c < 5 ? c : 5) * 0.2f;
    }
    // -------- transpose conv outputs -> LDS bf16 (reusing sef region) + row norms --------
    #pragma unroll
    for (int i = 0; i < 32; ++i) scb[i * SCST + tid] = f2bf(accA[i]);
    #pragma unroll
    for (int i = 0; i < 28; ++i) scb[(32 + i) * SCST + tid] = f2bf(accB[i]);
    #pragma unroll
    for (int i = 0; i < 32; ++i) {
        float s = accA[i] * accA[i];
        #pragma unroll
        for (int off = 32; off > 0; off >>= 1) s += __shfl_down(s, off, 64);
        if (lane == 0) atomicAdd(&scn[i], s);
    }
    #pragma unroll
    for (int i = 0; i < 28; ++i) {
        float s = accB[i] * accB[i];
        #pragma unroll
        for (int off = 32; off > 0; off >>= 1) s += __shfl_down(s, off, 64);
        if (lane == 0) atomicAdd(&scn[32 + i], s);
    }
    __syncthreads();
    if (tid < LSS) scn[tid] = 1.f / sqrtf(scn[tid]);
    __syncthreads();

    // -------- sim_sen dots (bf16 sc from LDS, fp32 qc from global) --------
    const float* qcb = qc + (size_t)b * LQQ * FF;
    for (int p = tid; p < LQQ * LSS; p += 256) {
        int l = p >> 5, q = p & 31;
        const unsigned short* sr = &scb[l * SCST];
        const float* qrow = qcb + q * FF;
        float s = 0.f;
        for (int k = 0; k < FF; k += 4) {
            uint2 xz = *(const uint2*)(sr + k);
            float4 y = *(const float4*)(qrow + k);
            s += bflo(xz.x) * y.x + bfhi(xz.x) * y.y + bflo(xz.y) * y.z + bfhi(xz.y) * y.w;
        }
        sim[q * 65 + l] = s * qciv[q] * scn[l] * qm[q] * (sid[l] > 0 ? 1.f : 0.f);
    }
    __syncthreads();
    // -------- pool sen + linear + sigmoid --------
    if (tid < LQQ) {
        int q = tid;
        float t0 = -1e30f, t1 = -1e30f, t2 = -1e30f, t3 = -1e30f, t4 = -1e30f;
        for (int l = 0; l < LSS; ++l) {
            float v = sim[q * 65 + l];
            if (v > t4) {
                if (v > t0)      { t4 = t3; t3 = t2; t2 = t1; t1 = t0; t0 = v; }
                else if (v > t1) { t4 = t3; t3 = t2; t2 = t1; t1 = v; }
                else if (v > t2) { t4 = t3; t3 = t2; t2 = v; }
                else if (v > t3) { t4 = t3; t3 = v; }
                else               t4 = v;
            }
        }
        float smax = t0, smean = (t0 + t1 + t2 + t3 + t4) * 0.2f;
        float z = featq[q][0] * W6[0] + featq[q][1] * W6[1] + smax * W6[2] + smean * W6[3]
                + featq[q][4] * W6[4] + featq[q][5] * W6[5] + b1[0];
        pr[q] = 1.f / (1.f + expf(-z));
    }
    __syncthreads();
    if (tid == 0) {
        float s = 0.f;
        for (int q = 0; q < LQQ; ++q) s += pr[q];
        d_out[1 + (size_t)b * NSS + n] = s * (1.f / 32.f);
    }
}

// ---------------- k_final: doc max + both BCEs + loss
__global__ __launch_bounds__(256) void k_final(const int* __restrict__ tsent,
                                               const int* __restrict__ tdoc,
                                               float* __restrict__ d_out) {
    const int tid = threadIdx.x;
    __shared__ float sh[256];
    __shared__ float docs[VB];
    if (tid < VB) {
        float m = -1e30f;
        for (int nn = 0; nn < NSS; ++nn) m = fmaxf(m, d_out[1 + tid * NSS + nn]);
        docs[tid] = m;
        d_out[1 + VB * NSS + tid] = m;
    }
    float s = 0.f;
    for (int i = tid; i < VB * NSS; i += 256) {
        float p = d_out[1 + i];
        p = fminf(fmaxf(p, 1e-7f), 1.f - 1e-7f);
        float t = (float)tsent[i];
        s += t * logf(p) + (1.f - t) * log1pf(-p);
    }
    sh[tid] = s;
    __syncthreads();
    for (int st = 128; st > 0; st >>= 1) {
        if (tid < st) sh[tid] += sh[tid + st];
        __syncthreads();
    }
    float ls = 0.f;
    if (tid == 0) ls = -sh[0] / (float)(VB * NSS);
    __syncthreads();
    float s2 = 0.f;
    if (tid < VB) {
        float p = fminf(fmaxf(docs[tid], 1e-7f), 1.f - 1e-7f);
        float t = (float)tdoc[tid];
        s2 = t * logf(p) + (1.f - t) * log1pf(-p);
    }
    sh[tid] = s2;
    __syncthreads();
    for (int st = 128; st > 0; st >>= 1) {
        if (tid < st) sh[tid] += sh[tid + st];
        __syncthreads();
    }
    if (tid == 0) {
        float ld = -sh[0] / (float)VB;
        d_out[0] = 0.5f * (ls + ld);
    }
}

extern "C" void kernel_launch(void* const* d_in, const int* in_sizes, int n_in,
                              void* d_out, int out_size, void* d_ws, size_t ws_size,
                              hipStream_t stream) {
    const int*   sentences = (const int*)d_in[0];
    const int*   question  = (const int*)d_in[1];
    const int*   tsent     = (const int*)d_in[2];
    const int*   tdoc      = (const int*)d_in[3];
    const float* embeds    = (const float*)d_in[4];
    const float* filters   = (const float*)d_in[5];
    const float* W6        = (const float*)d_in[6];
    const float* b1        = (const float*)d_in[7];
    float* out = (float*)d_out;

    float* ws     = (float*)d_ws;
    float* qe     = ws;                 // 64*34*300 = 652800 floats
    float* q_inv  = qe + 652800;        // 2048
    float* qc     = q_inv + 2048;       // 64*32*256 = 524288
    float* qc_inv = qc + 524288;        // 2048
    // total ws use: ~4.7 MB

    k_qprep<<<VB, 256, 0, stream>>>(question, embeds, qe, q_inv);
    k_qconv<<<VB * 8, 256, 0, stream>>>(qe, filters, qc, qc_inv);
    k_sent<<<VB * NSS, 256, 0, stream>>>(sentences, question, embeds, filters,
                                         qe, q_inv, qc, qc_inv, W6, b1, out);
    k_final<<<1, 256, 0, stream>>>(tsent, tdoc, out);
}

// Round 2
// 3349.608 us; speedup vs baseline: 1.0044x; 1.0044x over previous
//
#include <hip/hip_runtime.h>
#include <math.h>

// Problem constants (Posit_Drmm_Modeler)
#define VB  64      // batch
#define NSS 50      // sentences per doc
#define LSS 60      // sentence length
#define LQQ 32      // question length
#define DD  300     // embedding dim
#define FF  256     // filters
// LDS strides
#define SEST 308    // se row stride (floats): 308%32=20 -> 8 rows apart share banks (8-way worst)
#define SCST 264    // sc row stride (bf16 elems): 8B-aligned rows for uint2 reads

__device__ __forceinline__ unsigned short f2bf(float v) {
    unsigned int x = __float_as_uint(v);
    x += 0x7fffu + ((x >> 16) & 1u);          // RNE
    return (unsigned short)(x >> 16);
}
__device__ __forceinline__ float bflo(unsigned int u) { return __uint_as_float(u << 16); }
__device__ __forceinline__ float bfhi(unsigned int u) { return __uint_as_float(u & 0xffff0000u); }

// ---------------- k_qprep: gather question embeddings (fp32, rows 32..33 zero-padded) + row inv-norms
__global__ __launch_bounds__(256) void k_qprep(const int* __restrict__ question,
                                               const float* __restrict__ embeds,
                                               float* __restrict__ qe,
                                               float* __restrict__ q_inv) {
    const int b = blockIdx.x, tid = threadIdx.x, lane = tid & 63, wv = tid >> 6;
    float* qeb = qe + (size_t)b * 34 * DD;
    for (int idx = tid; idx < 34 * DD; idx += 256) {
        int r = idx / DD, d = idx - r * DD;
        float v = 0.f;
        if (r < LQQ) v = embeds[(size_t)question[b * LQQ + r] * DD + d];
        qeb[idx] = v;
    }
    __syncthreads();
    for (int row = wv; row < LQQ; row += 4) {
        float s = 0.f;
        for (int d = lane; d < DD; d += 64) { float v = qeb[row * DD + d]; s += v * v; }
        #pragma unroll
        for (int off = 32; off > 0; off >>= 1) s += __shfl_down(s, off, 64);
        if (lane == 0) q_inv[b * LQQ + row] = 1.f / sqrtf(s);
    }
}

// ---------------- k_qconv: question conv (forward window, zero pad at end) + inv-norm over F
// grid: VB*8, each WG does 4 l-positions x 256 filters. thread = filter.
__global__ __launch_bounds__(256) void k_qconv(const float* __restrict__ qe,
                                               const float* __restrict__ filters,
                                               float* __restrict__ qc,
                                               float* __restrict__ qc_inv) {
    const int blk = blockIdx.x, b = blk >> 3, l0 = (blk & 7) * 4;
    const int tid = threadIdx.x;
    __shared__ __align__(16) float sq[6 * DD];   // rows l0..l0+5 (<=33, padded rows are zero)
    __shared__ float red[256];
    const float* qeb = qe + (size_t)b * 34 * DD + (size_t)l0 * DD;
    for (int idx = tid; idx < 6 * DD; idx += 256) sq[idx] = qeb[idx];
    __syncthreads();
    const float* frow = filters + (size_t)tid * 900;
    float acc[4] = {0.f, 0.f, 0.f, 0.f};
    for (int t = 0; t < 3; ++t) {
        const float* ft = frow + t * DD;
        const float* st = sq + t * DD;
        for (int d4 = 0; d4 < 75; ++d4) {
            float4 w = *(const float4*)(ft + d4 * 4);
            #pragma unroll
            for (int i = 0; i < 4; ++i) {
                float4 x = *(const float4*)(st + i * DD + d4 * 4);
                acc[i] += w.x * x.x + w.y * x.y + w.z * x.z + w.w * x.w;
            }
        }
    }
    #pragma unroll
    for (int i = 0; i < 4; ++i)
        qc[((size_t)b * LQQ + l0 + i) * FF + tid] = acc[i];
    for (int i = 0; i < 4; ++i) {
        red[tid] = acc[i] * acc[i];
        __syncthreads();
        for (int s = 128; s > 0; s >>= 1) {
            if (tid < s) red[tid] += red[tid + s];
            __syncthreads();
        }
        if (tid == 0) qc_inv[(size_t)b * LQQ + l0 + i] = 1.f / sqrtf(red[0]);
        __syncthreads();
    }
}

// ---------------- k_sent: fully fused per-(b,n): gather + sim_ins + conv + sim_sen + pool + sigmoid-mean
__global__ __launch_bounds__(256) void k_sent(
    const int* __restrict__ sentences, const int* __restrict__ question,
    const float* __restrict__ embeds, const float* __restrict__ filters,
    const float* __restrict__ qe, const float* __restrict__ q_inv,
    const float* __restrict__ qc, const float* __restrict__ qc_inv,
    const float* __restrict__ W6, const float* __restrict__ b1,
    float* __restrict__ d_out) {
    const int blk = blockIdx.x;
    const int b = blk / NSS, n = blk - b * NSS;
    const int tid = threadIdx.x, lane = tid & 63, wv = tid >> 6;

    __shared__ __align__(16) float sef[34 * SEST];   // 41,888 B; later reused as bf16 sc (60*264*2=31,680 B)
    __shared__ float sim[LQQ * 65];                  // 8,320 B; reused ins -> sen
    __shared__ float sinv[LSS];
    __shared__ float scn[LSS];
    __shared__ int   sid[LSS];
    __shared__ int   qid[LQQ];
    __shared__ float qm[LQQ];
    __shared__ float qiv[LQQ];
    __shared__ float qciv[LQQ];
    __shared__ float featq[LQQ][6];
    __shared__ float pr[LQQ];
    unsigned short* scb = (unsigned short*)sef;

    if (tid < LSS) { sid[tid] = sentences[((size_t)b * NSS + n) * LSS + tid]; scn[tid] = 0.f; }
    if (tid < LQQ) {
        int qi = question[b * LQQ + tid];
        qid[tid] = qi; qm[tid] = qi > 0 ? 1.f : 0.f;
        qiv[tid]  = q_inv[b * LQQ + tid];
        qciv[tid] = qc_inv[b * LQQ + tid];
    }
    __syncthreads();

    float accA[32], accB[28];
    #pragma unroll
    for (int i = 0; i < 32; ++i) accA[i] = 0.f;
    #pragma unroll
    for (int i = 0; i < 28; ++i) accB[i] = 0.f;

    const float* frow = filters + (size_t)tid * 900;
    const float* qeb  = qe + (size_t)b * 34 * DD;

    // ======== PASS 0: stage sentence rows 0..33 (all real) ========
    for (int idx = tid; idx < 34 * DD; idx += 256) {
        int r = idx / DD, d = idx - r * DD;
        sef[r * SEST + d] = embeds[(size_t)sid[r] * DD + d];
    }
    __syncthreads();
    for (int row = wv; row < 34; row += 4) {          // inv-norms rows 0..33
        float s = 0.f;
        for (int d = lane; d < DD; d += 64) { float v = sef[row * SEST + d]; s += v * v; }
        #pragma unroll
        for (int off = 32; off > 0; off >>= 1) s += __shfl_down(s, off, 64);
        if (lane == 0) sinv[row] = 1.f / sqrtf(s);
    }
    __syncthreads();
    // sim_ins for l = 0..33 (32 lanes share a row -> broadcast LDS reads)
    for (int p = tid; p < LQQ * 34; p += 256) {
        int l = p >> 5, q = p & 31;
        const float* srow = &sef[l * SEST];
        const float* qrow = qeb + q * DD;
        float s = 0.f;
        for (int k = 0; k < DD; k += 4) {
            float4 x = *(const float4*)(srow + k);
            float4 y = *(const float4*)(qrow + k);
            s += x.x * y.x + x.y * y.y + x.z * y.z + x.w * y.w;
        }
        sim[q * 65 + l] = s * qiv[q] * sinv[l] * qm[q] * (sid[l] > 0 ? 1.f : 0.f);
    }
    // conv accumulate l = 0..31 (windows within rows 0..33)
    for (int t = 0; t < 3; ++t) {
        const float* ft = frow + t * DD;
        for (int d4 = 0; d4 < 75; ++d4) {
            float4 w = *(const float4*)(ft + d4 * 4);
            const float* base = &sef[t * SEST + d4 * 4];
            #pragma unroll
            for (int i = 0; i < 32; ++i) {
                float4 x = *(const float4*)(base + i * SEST);
                accA[i] += w.x * x.x + w.y * x.y + w.z * x.z + w.w * x.w;
            }
        }
    }
    __syncthreads();

    // ======== PASS 1: stage rows 32..63 into slots r=row-32 (rows >=60 are zero) ========
    for (int idx = tid; idx < 32 * DD; idx += 256) {
        int r = idx / DD, d = idx - r * DD;
        int row = 32 + r;
        float v = 0.f;
        if (row < LSS) v = embeds[(size_t)sid[row] * DD + d];
        sef[r * SEST + d] = v;
    }
    __syncthreads();
    for (int row = 34 + wv; row < LSS; row += 4) {    // inv-norms rows 34..59
        float s = 0.f; int r = row - 32;
        for (int d = lane; d < DD; d += 64) { float v = sef[r * SEST + d]; s += v * v; }
        #pragma unroll
        for (int off = 32; off > 0; off >>= 1) s += __shfl_down(s, off, 64);
        if (lane == 0) sinv[row] = 1.f / sqrtf(s);
    }
    __syncthreads();
    // sim_ins for l = 34..59
    for (int p = tid; p < LQQ * 26; p += 256) {
        int l = 34 + (p >> 5), q = p & 31;
        const float* srow = &sef[(l - 32) * SEST];
        const float* qrow = qeb + q * DD;
        float s = 0.f;
        for (int k = 0; k < DD; k += 4) {
            float4 x = *(const float4*)(srow + k);
            float4 y = *(const float4*)(qrow + k);
            s += x.x * y.x + x.y * y.y + x.z * y.z + x.w * y.w;
        }
        sim[q * 65 + l] = s * qiv[q] * sinv[l] * qm[q] * (sid[l] > 0 ? 1.f : 0.f);
    }
    // conv accumulate l = 32..59 (l=32+i, window slot = i+t)
    for (int t = 0; t < 3; ++t) {
        const float* ft = frow + t * DD;
        for (int d4 = 0; d4 < 75; ++d4) {
            float4 w = *(const float4*)(ft + d4 * 4);
            const float* base = &sef[t * SEST + d4 * 4];
            #pragma unroll
            for (int i = 0; i < 28; ++i) {
                float4 x = *(const float4*)(base + i * SEST);
                accB[i] += w.x * x.x + w.y * x.y + w.z * x.z + w.w * x.w;
            }
        }
    }
    __syncthreads();   // sef reads done; sim_ins complete

    // -------- pool ins + exact-match (oh) channel --------
    if (tid < LQQ) {
        int q = tid;
        float t0 = -1e30f, t1 = -1e30f, t2 = -1e30f, t3 = -1e30f, t4 = -1e30f;
        for (int l = 0; l < LSS; ++l) {
            float v = sim[q * 65 + l];
            if (v > t4) {
                if (v > t0)      { t4 = t3; t3 = t2; t2 = t1; t1 = t0; t0 = v; }
                else if (v > t1) { t4 = t3; t3 = t2; t2 = t1; t1 = v; }
                else if (v > t2) { t4 = t3; t3 = t2; t2 = v; }
                else if (v > t3) { t4 = t3; t3 = v; }
                else               t4 = v;
            }
        }
        featq[q][0] = t0;
        featq[q][1] = (t0 + t1 + t2 + t3 + t4) * 0.2f;
        // oh channel: cos>=1-1e-5  <=>  identical token id (incl. pad==pad), UNMASKED as in ref
        int qi = qid[q], c = 0;
        for (int l = 0; l < LSS; ++l) c += (sid[l] == qi) ? 1 : 0;
        featq[q][4] = c > 0 ? 1.f : 0.f;
        featq[q][5] = (float)(c < 5 ? c : 5) * 0.2f;
    }
    // -------- transpose conv outputs -> LDS bf16 (reusing sef region) + row norms --------
    #pragma unroll
    for (int i = 0; i < 32; ++i) scb[i * SCST + tid] = f2bf(accA[i]);
    #pragma unroll
    for (int i = 0; i < 28; ++i) scb[(32 + i) * SCST + tid] = f2bf(accB[i]);
    #pragma unroll
    for (int i = 0; i < 32; ++i) {
        float s = accA[i] * accA[i];
        #pragma unroll
        for (int off = 32; off > 0; off >>= 1) s += __shfl_down(s, off, 64);
        if (lane == 0) atomicAdd(&scn[i], s);
    }
    #pragma unroll
    for (int i = 0; i < 28; ++i) {
        float s = accB[i] * accB[i];
        #pragma unroll
        for (int off = 32; off > 0; off >>= 1) s += __shfl_down(s, off, 64);
        if (lane == 0) atomicAdd(&scn[32 + i], s);
    }
    __syncthreads();
    if (tid < LSS) scn[tid] = 1.f / sqrtf(scn[tid]);
    __syncthreads();

    // -------- sim_sen dots (bf16 sc from LDS, fp32 qc from global) --------
    const float* qcb = qc + (size_t)b * LQQ * FF;
    for (int p = tid; p < LQQ * LSS; p += 256) {
        int l = p >> 5, q = p & 31;
        const unsigned short* sr = &scb[l * SCST];
        const float* qrow = qcb + q * FF;
        float s = 0.f;
        for (int k = 0; k < FF; k += 4) {
            uint2 xz = *(const uint2*)(sr + k);
            float4 y = *(const float4*)(qrow + k);
            s += bflo(xz.x) * y.x + bfhi(xz.x) * y.y + bflo(xz.y) * y.z + bfhi(xz.y) * y.w;
        }
        sim[q * 65 + l] = s * qciv[q] * scn[l] * qm[q] * (sid[l] > 0 ? 1.f : 0.f);
    }
    __syncthreads();
    // -------- pool sen + linear + sigmoid --------
    if (tid < LQQ) {
        int q = tid;
        float t0 = -1e30f, t1 = -1e30f, t2 = -1e30f, t3 = -1e30f, t4 = -1e30f;
        for (int l = 0; l < LSS; ++l) {
            float v = sim[q * 65 + l];
            if (v > t4) {
                if (v > t0)      { t4 = t3; t3 = t2; t2 = t1; t1 = t0; t0 = v; }
                else if (v > t1) { t4 = t3; t3 = t2; t2 = t1; t1 = v; }
                else if (v > t2) { t4 = t3; t3 = t2; t2 = v; }
                else if (v > t3) { t4 = t3; t3 = v; }
                else               t4 = v;
            }
        }
        float smax = t0, smean = (t0 + t1 + t2 + t3 + t4) * 0.2f;
        float z = featq[q][0] * W6[0] + featq[q][1] * W6[1] + smax * W6[2] + smean * W6[3]
                + featq[q][4] * W6[4] + featq[q][5] * W6[5] + b1[0];
        pr[q] = 1.f / (1.f + expf(-z));
    }
    __syncthreads();
    if (tid == 0) {
        float s = 0.f;
        for (int q = 0; q < LQQ; ++q) s += pr[q];
        d_out[1 + (size_t)b * NSS + n] = s * (1.f / 32.f);
    }
}

// ---------------- k_final: doc max + both BCEs + loss
__global__ __launch_bounds__(256) void k_final(const int* __restrict__ tsent,
                                               const int* __restrict__ tdoc,
                                               float* __restrict__ d_out) {
    const int tid = threadIdx.x;
    __shared__ float sh[256];
    __shared__ float docs[VB];
    if (tid < VB) {
        float m = -1e30f;
        for (int nn = 0; nn < NSS; ++nn) m = fmaxf(m, d_out[1 + tid * NSS + nn]);
        docs[tid] = m;
        d_out[1 + VB * NSS + tid] = m;
    }
    float s = 0.f;
    for (int i = tid; i < VB * NSS; i += 256) {
        float p = d_out[1 + i];
        p = fminf(fmaxf(p, 1e-7f), 1.f - 1e-7f);
        float t = (float)tsent[i];
        s += t * logf(p) + (1.f - t) * log1pf(-p);
    }
    sh[tid] = s;
    __syncthreads();
    for (int st = 128; st > 0; st >>= 1) {
        if (tid < st) sh[tid] += sh[tid + st];
        __syncthreads();
    }
    float ls = 0.f;
    if (tid == 0) ls = -sh[0] / (float)(VB * NSS);
    __syncthreads();
    float s2 = 0.f;
    if (tid < VB) {
        float p = fminf(fmaxf(docs[tid], 1e-7f), 1.f - 1e-7f);
        float t = (float)tdoc[tid];
        s2 = t * logf(p) + (1.f - t) * log1pf(-p);
    }
    sh[tid] = s2;
    __syncthreads();
    for (int st = 128; st > 0; st >>= 1) {
        if (tid < st) sh[tid] += sh[tid + st];
        __syncthreads();
    }
    if (tid == 0) {
        float ld = -sh[0] / (float)VB;
        d_out[0] = 0.5f * (ls + ld);
    }
}

extern "C" void kernel_launch(void* const* d_in, const int* in_sizes, int n_in,
                              void* d_out, int out_size, void* d_ws, size_t ws_size,
                              hipStream_t stream) {
    const int*   sentences = (const int*)d_in[0];
    const int*   question  = (const int*)d_in[1];
    const int*   tsent     = (const int*)d_in[2];
    const int*   tdoc      = (const int*)d_in[3];
    const float* embeds    = (const float*)d_in[4];
    const float* filters   = (const float*)d_in[5];
    const float* W6        = (const float*)d_in[6];
    const float* b1        = (const float*)d_in[7];
    float* out = (float*)d_out;

    float* ws     = (float*)d_ws;
    float* qe     = ws;                 // 64*34*300 = 652800 floats
    float* q_inv  = qe + 652800;        // 2048
    float* qc     = q_inv + 2048;       // 64*32*256 = 524288
    float* qc_inv = qc + 524288;        // 2048
    // total ws use: ~4.7 MB

    k_qprep<<<VB, 256, 0, stream>>>(question, embeds, qe, q_inv);
    k_qconv<<<VB * 8, 256, 0, stream>>>(qe, filters, qc, qc_inv);
    k_sent<<<VB * NSS, 256, 0, stream>>>(sentences, question, embeds, filters,
                                         qe, q_inv, qc, qc_inv, W6, b1, out);
    k_final<<<1, 256, 0, stream>>>(tsent, tdoc, out);
}

// Round 3
// 523.087 us; speedup vs baseline: 6.4317x; 6.4035x over previous
//
#include <hip/hip_runtime.h>
#include <math.h>

// Problem constants (Posit_Drmm_Modeler)
#define VB  64      // batch
#define NSS 50      // sentences per doc
#define LSS 60      // sentence length
#define LQQ 32      // question length
#define DD  300     // embedding dim
#define FF  256     // filters

#define SEST 312    // seb row stride (bf16): 312%8==0 -> 16B rows; bank step 156%32=28 -> 2-way (free)
#define SROWS 66    // rows 60..65 zero (conv A-frag overrun + M-pad)
#define SCST 264    // scb row stride (bf16): bank step 132%32=4 -> 2-way (free)
#define SIMST 66    // sim row stride (fp32): 2-way on pooling reads
#define KKC 29      // conv K-steps (K=928 incl. stride pads; filter zeros neutralize)
#define KKI 10      // sim_ins K-steps (K=320, qe zero-padded)
#define KKS 8       // sim_sen K-steps (K=256)

typedef __attribute__((ext_vector_type(8))) short bfrag;   // 8 x bf16 (4 VGPRs)
typedef __attribute__((ext_vector_type(4))) float ffrag;   // 4 x f32 acc

__device__ __forceinline__ unsigned short f2bf(float v) {
    unsigned int x = __float_as_uint(v);
    x += 0x7fffu + ((x >> 16) & 1u);          // RNE
    return (unsigned short)(x >> 16);
}
__device__ __forceinline__ float bf2f(unsigned short u) {
    return __uint_as_float(((unsigned int)u) << 16);
}

// ---------------- k_fprep: filters fp32 -> bf16 MFMA B-fragment order
// layout: [kk(29)][nt(16)][lane(64)][j(8)]; value = filt[f=nt*16+(lane&15)][k=kk*32+quad*8+j]
// with k -> (t=k/312, d=k%312), zero if t>=3 or d>=300.
__global__ __launch_bounds__(256) void k_fprep(const float* __restrict__ filters,
                                               unsigned short* __restrict__ filt_frag) {
    int idx = blockIdx.x * 256 + threadIdx.x;
    const int total = KKC * 16 * 64 * 8;
    if (idx >= total) return;
    int j = idx & 7, ln = (idx >> 3) & 63, nt = (idx >> 9) & 15, kk = idx >> 13;
    int f = nt * 16 + (ln & 15);
    int k = kk * 32 + ((ln >> 4) << 3) + j;
    int t = k / SEST, d = k - t * SEST;
    unsigned short v = 0;
    if (t < 3 && d < DD) v = f2bf(filters[f * 900 + t * DD + d]);
    filt_frag[idx] = v;
}

// ---------------- k_qprep: gather qe fp32 (rows 32..33 zero) + q_inv + qe A-fragments (bf16)
__global__ __launch_bounds__(256) void k_qprep(const int* __restrict__ question,
                                               const float* __restrict__ embeds,
                                               float* __restrict__ qe,
                                               float* __restrict__ q_inv,
                                               unsigned short* __restrict__ qe_frag) {
    const int b = blockIdx.x, tid = threadIdx.x, lane = tid & 63, wv = tid >> 6;
    float* qeb = qe + (size_t)b * 34 * DD;
    for (int idx = tid; idx < 34 * DD; idx += 256) {
        int r = idx / DD, d = idx - r * DD;
        float v = 0.f;
        if (r < LQQ) v = embeds[(size_t)question[b * LQQ + r] * DD + d];
        qeb[idx] = v;
    }
    __syncthreads();
    for (int row = wv; row < LQQ; row += 4) {
        float s = 0.f;
        for (int d = lane; d < DD; d += 64) { float v = qeb[row * DD + d]; s += v * v; }
        #pragma unroll
        for (int off = 32; off > 0; off >>= 1) s += __shfl_down(s, off, 64);
        if (lane == 0) q_inv[b * LQQ + row] = 1.f / sqrtf(s);
    }
    // A-fragments: [kk(10)][mt(2)][lane(64)][j(8)] per b
    for (int idx = tid; idx < KKI * 2 * 64 * 8; idx += 256) {
        int j = idx & 7, ln = (idx >> 3) & 63, mt = (idx >> 9) & 1, kk = idx >> 10;
        int q = mt * 16 + (ln & 15);
        int k = kk * 32 + ((ln >> 4) << 3) + j;
        float v = (k < DD) ? qeb[q * DD + k] : 0.f;
        qe_frag[(size_t)b * (KKI * 2 * 512) + idx] = f2bf(v);
    }
}

// ---------------- k_qconv: question conv fp32 + qc_inv + qc A-fragments (bf16)
__global__ __launch_bounds__(256) void k_qconv(const float* __restrict__ qe,
                                               const float* __restrict__ filters,
                                               unsigned short* __restrict__ qc_frag,
                                               float* __restrict__ qc_inv) {
    const int blk = blockIdx.x, b = blk >> 3, l0 = (blk & 7) * 4;
    const int tid = threadIdx.x;
    __shared__ __align__(16) float sq[6 * DD];
    __shared__ float red[256];
    const float* qeb = qe + (size_t)b * 34 * DD + (size_t)l0 * DD;
    for (int idx = tid; idx < 6 * DD; idx += 256) sq[idx] = qeb[idx];
    __syncthreads();
    const float* frow = filters + (size_t)tid * 900;
    float acc[4] = {0.f, 0.f, 0.f, 0.f};
    for (int t = 0; t < 3; ++t) {
        const float* ft = frow + t * DD;
        const float* st = sq + t * DD;
        for (int d4 = 0; d4 < 75; ++d4) {
            float4 wv = *(const float4*)(ft + d4 * 4);
            #pragma unroll
            for (int i = 0; i < 4; ++i) {
                float4 x = *(const float4*)(st + i * DD + d4 * 4);
                acc[i] += wv.x * x.x + wv.y * x.y + wv.z * x.z + wv.w * x.w;
            }
        }
    }
    // qc A-fragments: [kk(8)][mt(2)][lane(64)][j(8)] per b; A[m=q][k=f]
    {
        int kk = tid >> 5, quad = (tid >> 3) & 3, j = tid & 7;
        #pragma unroll
        for (int i = 0; i < 4; ++i) {
            int q = l0 + i;
            int mt = q >> 4, ln = quad * 16 + (q & 15);
            qc_frag[(size_t)b * 8192 + ((size_t)(kk * 2 + mt) * 64 + ln) * 8 + j] = f2bf(acc[i]);
        }
    }
    for (int i = 0; i < 4; ++i) {
        red[tid] = acc[i] * acc[i];
        __syncthreads();
        for (int s = 128; s > 0; s >>= 1) {
            if (tid < s) red[tid] += red[tid + s];
            __syncthreads();
        }
        if (tid == 0) qc_inv[(size_t)b * LQQ + l0 + i] = 1.f / sqrtf(red[0]);
        __syncthreads();
    }
}

// ---------------- k_sent: fused per-(b,n), MFMA for conv + sim_ins + sim_sen
__global__ __launch_bounds__(256, 3) void k_sent(
    const int* __restrict__ sentences, const int* __restrict__ question,
    const float* __restrict__ embeds,
    const unsigned short* __restrict__ filt_frag,
    const unsigned short* __restrict__ qe_frag,
    const unsigned short* __restrict__ qc_frag,
    const float* __restrict__ q_inv, const float* __restrict__ qc_inv,
    const float* __restrict__ W6, const float* __restrict__ b1,
    float* __restrict__ d_out) {
    const int blk = blockIdx.x;
    const int b = blk / NSS, n = blk - b * NSS;
    const int tid = threadIdx.x, lane = tid & 63, w = tid >> 6;
    const int quad = lane >> 4, m16 = lane & 15;

    __shared__ __align__(16) unsigned short seb[SROWS * SEST]; // 41,184 B; overlaid by scb after conv
    __shared__ __align__(16) float sim[LQQ * SIMST];           // 8,448 B
    __shared__ float sinv[64], scninv[64];
    __shared__ int sid[64];
    __shared__ int qid[LQQ];
    __shared__ float qm[LQQ], qiv[LQQ], qciv[LQQ];
    __shared__ float featq[LQQ][4];
    __shared__ float pr[LQQ];
    unsigned short* scb = seb;   // overlay: conv output [l][f] bf16 (60+4 zero rows x 264)

    if (tid < 64) sid[tid] = (tid < LSS) ? sentences[((size_t)b * NSS + n) * LSS + tid] : 0;
    if (tid < LQQ) {
        int qi = question[b * LQQ + tid];
        qid[tid] = qi; qm[tid] = qi > 0 ? 1.f : 0.f;
        qiv[tid] = q_inv[b * LQQ + tid]; qciv[tid] = qc_inv[b * LQQ + tid];
    }
    // zero seb row tails (d 300..311) and rows 60..65
    {
        ushort4 z4 = {0, 0, 0, 0};
        for (int i = tid; i < 180; i += 256) {
            int r = i / 3, c = 300 + (i - r * 3) * 4;
            *(ushort4*)(seb + r * SEST + c) = z4;
        }
        for (int i = tid; i < 468; i += 256) {
            int r = i / 78, c = (i - r * 78) * 4;
            *(ushort4*)(seb + (60 + r) * SEST + c) = z4;
        }
    }
    __syncthreads();
    // gather sentence embeddings -> bf16 LDS
    for (int i = tid; i < LSS * 75; i += 256) {
        int r = i / 75, c = (i - r * 75) * 4;
        float4 v = *(const float4*)(embeds + (size_t)sid[r] * DD + c);
        ushort4 h;
        h.x = f2bf(v.x); h.y = f2bf(v.y); h.z = f2bf(v.z); h.w = f2bf(v.w);
        *(ushort4*)(seb + r * SEST + c) = h;
    }
    __syncthreads();
    // row inv-norms from bf16 (4 lanes per row)
    if (tid < 240) {
        int r = tid >> 2, part = tid & 3;
        float s = 0.f;
        for (int c = part * 4; c < DD; c += 16) {
            uint2 u = *(const uint2*)(seb + r * SEST + c);
            float a0 = bf2f((unsigned short)(u.x & 0xffff)), a1 = bf2f((unsigned short)(u.x >> 16));
            float a2 = bf2f((unsigned short)(u.y & 0xffff)), a3 = bf2f((unsigned short)(u.y >> 16));
            s += a0 * a0 + a1 * a1 + a2 * a2 + a3 * a3;
        }
        s += __shfl_down(s, 2, 64);
        s += __shfl_down(s, 1, 64);
        if (part == 0) sinv[r] = 1.f / sqrtf(s);
    }
    if (tid >= 240 && tid < 244) sinv[60 + tid - 240] = 0.f;
    __syncthreads();

    // ======== conv GEMM: C[l=64][f=256] = seb-window[64x928] x filt[928x256] ========
    // wave w owns N-tiles w*4..w*4+3, all 4 M-tiles. No barriers in K-loop.
    ffrag acc[4][4];
    #pragma unroll
    for (int mt = 0; mt < 4; ++mt)
        #pragma unroll
        for (int i = 0; i < 4; ++i) acc[mt][i] = (ffrag)0.f;
    {
        const bfrag* fF = (const bfrag*)filt_frag;
        const int w4 = w * 4;
        for (int kk = 0; kk < KKC; ++kk) {
            const int kb = kk * 32 + quad * 8;
            bfrag a[4];
            #pragma unroll
            for (int mt = 0; mt < 4; ++mt)
                a[mt] = *(const bfrag*)(seb + (mt * 16 + m16) * SEST + kb);
            bfrag bb[4];
            #pragma unroll
            for (int i = 0; i < 4; ++i)
                bb[i] = fF[(kk * 16 + w4 + i) * 64 + lane];
            #pragma unroll
            for (int mt = 0; mt < 4; ++mt)
                #pragma unroll
                for (int i = 0; i < 4; ++i)
                    acc[mt][i] = __builtin_amdgcn_mfma_f32_16x16x32_bf16(a[mt], bb[i], acc[mt][i], 0, 0, 0);
        }
    }
    // ======== sim_ins GEMM: C[q=32][l=64] = qe[32x320] x seb^T ========
    {
        const bfrag* qF = (const bfrag*)qe_frag;
        const int mt = w >> 1, nt0 = (w & 1) * 2;
        ffrag c0 = (ffrag)0.f, c1 = (ffrag)0.f;
        for (int kk = 0; kk < KKI; ++kk) {
            bfrag aq = qF[((size_t)(b * KKI + kk) * 2 + mt) * 64 + lane];
            const int kb = kk * 32 + quad * 8;
            bfrag b0 = *(const bfrag*)(seb + (nt0 * 16 + m16) * SEST + kb);
            bfrag b1v = *(const bfrag*)(seb + ((nt0 + 1) * 16 + m16) * SEST + kb);
            c0 = __builtin_amdgcn_mfma_f32_16x16x32_bf16(aq, b0, c0, 0, 0, 0);
            c1 = __builtin_amdgcn_mfma_f32_16x16x32_bf16(aq, b1v, c1, 0, 0, 0);
        }
        const int l0_ = nt0 * 16 + m16, l1_ = (nt0 + 1) * 16 + m16;
        const float sm0 = sinv[l0_] * (sid[l0_] > 0 ? 1.f : 0.f);
        const float sm1 = sinv[l1_] * (sid[l1_] > 0 ? 1.f : 0.f);
        #pragma unroll
        for (int r = 0; r < 4; ++r) {
            int q = mt * 16 + quad * 4 + r;
            float sq_ = qiv[q] * qm[q];
            sim[q * SIMST + l0_] = c0[r] * sq_ * sm0;
            sim[q * SIMST + l1_] = c1[r] * sq_ * sm1;
        }
    }
    __syncthreads();   // all seb reads done; sim_ins visible

    // ======== conv C -> scb bf16 [l][f] (overlays seb) + zero rows 60..63 + pool_ins ========
    {
        ushort4 z4 = {0, 0, 0, 0};
        int r4 = 60 + (tid >> 6), c4 = (tid & 63) * 4;
        *(ushort4*)(scb + r4 * SCST + c4) = z4;
    }
    #pragma unroll
    for (int mt = 0; mt < 4; ++mt)
        #pragma unroll
        for (int i = 0; i < 4; ++i) {
            int f = (w * 4 + i) * 16 + m16;
            #pragma unroll
            for (int r = 0; r < 4; ++r) {
                int l = mt * 16 + quad * 4 + r;
                scb[l * SCST + f] = f2bf(acc[mt][i][r]);
            }
        }
    if (tid < LQQ) {   // pool_ins + exact-match channel (integer equality, incl pad==pad, unmasked)
        int q = tid;
        float t0 = -1e30f, t1 = -1e30f, t2 = -1e30f, t3 = -1e30f, t4 = -1e30f;
        for (int l = 0; l < LSS; ++l) {
            float v = sim[q * SIMST + l];
            if (v > t4) {
                if (v > t0)      { t4 = t3; t3 = t2; t2 = t1; t1 = t0; t0 = v; }
                else if (v > t1) { t4 = t3; t3 = t2; t2 = t1; t1 = v; }
                else if (v > t2) { t4 = t3; t3 = t2; t2 = v; }
                else if (v > t3) { t4 = t3; t3 = v; }
                else               t4 = v;
            }
        }
        featq[q][0] = t0;
        featq[q][1] = (t0 + t1 + t2 + t3 + t4) * 0.2f;
        int qi = qid[q], c = 0;
        for (int l = 0; l < LSS; ++l) c += (sid[l] == qi) ? 1 : 0;
        featq[q][2] = c > 0 ? 1.f : 0.f;
        featq[q][3] = (float)(c < 5 ? c : 5) * 0.2f;
    }
    __syncthreads();
    // scb row inv-norms
    if (tid < 240) {
        int r = tid >> 2, part = tid & 3;
        float s = 0.f;
        for (int c = part * 4; c < FF; c += 16) {
            uint2 u = *(const uint2*)(scb + r * SCST + c);
            float a0 = bf2f((unsigned short)(u.x & 0xffff)), a1 = bf2f((unsigned short)(u.x >> 16));
            float a2 = bf2f((unsigned short)(u.y & 0xffff)), a3 = bf2f((unsigned short)(u.y >> 16));
            s += a0 * a0 + a1 * a1 + a2 * a2 + a3 * a3;
        }
        s += __shfl_down(s, 2, 64);
        s += __shfl_down(s, 1, 64);
        if (part == 0) scninv[r] = 1.f / sqrtf(s);
    }
    if (tid >= 240 && tid < 244) scninv[60 + tid - 240] = 0.f;
    __syncthreads();
    // ======== sim_sen GEMM: C[q=32][l=64] = qc[32x256] x scb^T ========
    {
        const bfrag* qF = (const bfrag*)qc_frag;
        const int mt = w >> 1, nt0 = (w & 1) * 2;
        ffrag c0 = (ffrag)0.f, c1 = (ffrag)0.f;
        for (int kk = 0; kk < KKS; ++kk) {
            bfrag aq = qF[((size_t)(b * KKS + kk) * 2 + mt) * 64 + lane];
            const int kb = kk * 32 + quad * 8;
            bfrag b0 = *(const bfrag*)(scb + (nt0 * 16 + m16) * SCST + kb);
            bfrag b1v = *(const bfrag*)(scb + ((nt0 + 1) * 16 + m16) * SCST + kb);
            c0 = __builtin_amdgcn_mfma_f32_16x16x32_bf16(aq, b0, c0, 0, 0, 0);
            c1 = __builtin_amdgcn_mfma_f32_16x16x32_bf16(aq, b1v, c1, 0, 0, 0);
        }
        const int l0_ = nt0 * 16 + m16, l1_ = (nt0 + 1) * 16 + m16;
        const float sm0 = scninv[l0_] * (sid[l0_] > 0 ? 1.f : 0.f);
        const float sm1 = scninv[l1_] * (sid[l1_] > 0 ? 1.f : 0.f);
        #pragma unroll
        for (int r = 0; r < 4; ++r) {
            int q = mt * 16 + quad * 4 + r;
            float sq_ = qciv[q] * qm[q];
            sim[q * SIMST + l0_] = c0[r] * sq_ * sm0;
            sim[q * SIMST + l1_] = c1[r] * sq_ * sm1;
        }
    }
    __syncthreads();
    if (tid < LQQ) {   // pool_sen + linear + sigmoid
        int q = tid;
        float t0 = -1e30f, t1 = -1e30f, t2 = -1e30f, t3 = -1e30f, t4 = -1e30f;
        for (int l = 0; l < LSS; ++l) {
            float v = sim[q * SIMST + l];
            if (v > t4) {
                if (v > t0)      { t4 = t3; t3 = t2; t2 = t1; t1 = t0; t0 = v; }
                else if (v > t1) { t4 = t3; t3 = t2; t2 = t1; t1 = v; }
                else if (v > t2) { t4 = t3; t3 = t2; t2 = v; }
                else if (v > t3) { t4 = t3; t3 = v; }
                else               t4 = v;
            }
        }
        float smax = t0, smean = (t0 + t1 + t2 + t3 + t4) * 0.2f;
        float z = featq[q][0] * W6[0] + featq[q][1] * W6[1] + smax * W6[2] + smean * W6[3]
                + featq[q][2] * W6[4] + featq[q][3] * W6[5] + b1[0];
        pr[q] = 1.f / (1.f + expf(-z));
    }
    __syncthreads();
    if (tid == 0) {
        float s = 0.f;
        for (int q = 0; q < LQQ; ++q) s += pr[q];
        d_out[1 + (size_t)b * NSS + n] = s * (1.f / 32.f);
    }
}

// ---------------- k_final: doc max + both BCEs + loss
__global__ __launch_bounds__(256) void k_final(const int* __restrict__ tsent,
                                               const int* __restrict__ tdoc,
                                               float* __restrict__ d_out) {
    const int tid = threadIdx.x;
    __shared__ float sh[256];
    __shared__ float docs[VB];
    if (tid < VB) {
        float m = -1e30f;
        for (int nn = 0; nn < NSS; ++nn) m = fmaxf(m, d_out[1 + tid * NSS + nn]);
        docs[tid] = m;
        d_out[1 + VB * NSS + tid] = m;
    }
    float s = 0.f;
    for (int i = tid; i < VB * NSS; i += 256) {
        float p = d_out[1 + i];
        p = fminf(fmaxf(p, 1e-7f), 1.f - 1e-7f);
        float t = (float)tsent[i];
        s += t * logf(p) + (1.f - t) * log1pf(-p);
    }
    sh[tid] = s;
    __syncthreads();
    for (int st = 128; st > 0; st >>= 1) {
        if (tid < st) sh[tid] += sh[tid + st];
        __syncthreads();
    }
    float ls = 0.f;
    if (tid == 0) ls = -sh[0] / (float)(VB * NSS);
    __syncthreads();
    float s2 = 0.f;
    if (tid < VB) {
        float p = fminf(fmaxf(docs[tid], 1e-7f), 1.f - 1e-7f);
        float t = (float)tdoc[tid];
        s2 = t * logf(p) + (1.f - t) * log1pf(-p);
    }
    sh[tid] = s2;
    __syncthreads();
    for (int st = 128; st > 0; st >>= 1) {
        if (tid < st) sh[tid] += sh[tid + st];
        __syncthreads();
    }
    if (tid == 0) {
        float ld = -sh[0] / (float)VB;
        d_out[0] = 0.5f * (ls + ld);
    }
}

extern "C" void kernel_launch(void* const* d_in, const int* in_sizes, int n_in,
                              void* d_out, int out_size, void* d_ws, size_t ws_size,
                              hipStream_t stream) {
    const int*   sentences = (const int*)d_in[0];
    const int*   question  = (const int*)d_in[1];
    const int*   tsent     = (const int*)d_in[2];
    const int*   tdoc      = (const int*)d_in[3];
    const float* embeds    = (const float*)d_in[4];
    const float* filters   = (const float*)d_in[5];
    const float* W6        = (const float*)d_in[6];
    const float* b1        = (const float*)d_in[7];
    float* out = (float*)d_out;

    float* ws = (float*)d_ws;
    float* qe     = ws;                         // 652,800 f
    float* q_inv  = qe + 652800;                // 2,048 f
    float* qc_inv = q_inv + 2048;               // 2,048 f
    unsigned short* qe_frag  = (unsigned short*)(qc_inv + 2048);  // 655,360 sh (16B-aligned)
    unsigned short* qc_frag  = qe_frag + 655360;                  // 524,288 sh
    unsigned short* filt_frag = qc_frag + 524288;                 // 237,568 sh  (total ~5.5 MB)

    k_fprep<<<928, 256, 0, stream>>>(filters, filt_frag);
    k_qprep<<<VB, 256, 0, stream>>>(question, embeds, qe, q_inv, qe_frag);
    k_qconv<<<VB * 8, 256, 0, stream>>>(qe, filters, qc_frag, qc_inv);
    k_sent<<<VB * NSS, 256, 0, stream>>>(sentences, question, embeds,
                                         filt_frag, qe_frag, qc_frag,
                                         q_inv, qc_inv, W6, b1, out);
    k_final<<<1, 256, 0, stream>>>(tsent, tdoc, out);
}